// Round 2
// baseline (1048.984 us; speedup 1.0000x reference)
//
#include <hip/hip_runtime.h>

#define N_RES   20000
#define N_EDGE  640000
#define NFEAT   340

// freq[m] = exp(2m * (-ln(10000)/16)) = 10^(-m/2)
__device__ __constant__ float c_freq[8] = {
    1.0f, 0.31622776601683794f, 0.1f, 0.031622776601683794f,
    0.01f, 0.0031622776601683794f, 0.001f, 0.00031622776601683794f};

// Per-residue precompute: bb[12] (N,CA,C,virtual CB), local[12] = R^T(bb-t),
// R[9], t[3]  -> 36 floats per residue in workspace.
extern "C" __global__ __launch_bounds__(256)
void residue_prep(const float* __restrict__ atom14,
                  const float* __restrict__ rigids7,
                  float* __restrict__ res) {
    int r = blockIdx.x * 256 + threadIdx.x;
    if (r >= N_RES) return;

    const float* a = atom14 + (size_t)r * 42;  // 14 atoms * 3
    float nx  = a[0], ny  = a[1], nz  = a[2];
    float cax = a[3], cay = a[4], caz = a[5];
    float cx  = a[6], cy  = a[7], cz  = a[8];

    // virtual CB
    float bx = cax - nx, by = cay - ny, bz = caz - nz;     // b  = ca - n
    float ex = cx - cax, ey = cy - cay, ez = cz - caz;     // cc = c - ca
    float ax = by * ez - bz * ey;                          // a = cross(b, cc)
    float ay = bz * ex - bx * ez;
    float az = bx * ey - by * ex;
    float cbx = -0.58273431f * ax + 0.56802827f * bx - 0.54067466f * ex + cax;
    float cby = -0.58273431f * ay + 0.56802827f * by - 0.54067466f * ey + cay;
    float cbz = -0.58273431f * az + 0.56802827f * bz - 0.54067466f * ez + caz;

    const float* q7 = rigids7 + (size_t)r * 7;
    float qw = q7[0], qx = q7[1], qy = q7[2], qz = q7[3];
    float inv = 1.0f / sqrtf(qw * qw + qx * qx + qy * qy + qz * qz);
    qw *= inv; qx *= inv; qy *= inv; qz *= inv;
    float tx = q7[4], ty = q7[5], tz = q7[6];

    // R[j*3+i] : row j, col i (matches _quat_to_rot stacking)
    float R[9];
    R[0] = 1.0f - 2.0f * (qy * qy + qz * qz);
    R[1] = 2.0f * (qx * qy - qw * qz);
    R[2] = 2.0f * (qx * qz + qw * qy);
    R[3] = 2.0f * (qx * qy + qw * qz);
    R[4] = 1.0f - 2.0f * (qx * qx + qz * qz);
    R[5] = 2.0f * (qy * qz - qw * qx);
    R[6] = 2.0f * (qx * qz - qw * qy);
    R[7] = 2.0f * (qy * qz + qw * qx);
    R[8] = 1.0f - 2.0f * (qx * qx + qy * qy);

    float bb[12] = {nx, ny, nz, cax, cay, caz, cx, cy, cz, cbx, cby, cbz};

    float* o = res + (size_t)r * 36;
    #pragma unroll
    for (int k = 0; k < 12; ++k) o[k] = bb[k];
    // local[k][i] = sum_j R[j][i] * (bb[k][j] - t[j])   (R^T * x)
    #pragma unroll
    for (int k = 0; k < 4; ++k) {
        float x0 = bb[k * 3 + 0] - tx;
        float x1 = bb[k * 3 + 1] - ty;
        float x2 = bb[k * 3 + 2] - tz;
        #pragma unroll
        for (int i = 0; i < 3; ++i)
            o[12 + k * 3 + i] = R[i] * x0 + R[3 + i] * x1 + R[6 + i] * x2;
    }
    #pragma unroll
    for (int j = 0; j < 9; ++j) o[24 + j] = R[j];
    o[33] = tx; o[34] = ty; o[35] = tz;
}

// Positional-encoding table: dpos = dst-src is an INTEGER in [-19999,19999].
// tab[row][0..7] = cos(d*freq[m]), tab[row][8..15] = sin(d*freq[m]), d = row-19999.
// Same cosf/sinf expressions as the passing kernel -> bitwise-identical features.
extern "C" __global__ __launch_bounds__(256)
void pos_table(float* __restrict__ tab) {
    int idx = blockIdx.x * 256 + threadIdx.x;   // 0 .. 640000-1 (40000 rows * 16)
    int row = idx >> 4;
    int m = idx & 15;
    float d = (float)(row - 19999);
    float ang = d * c_freq[m & 7];
    tab[idx] = (m < 8) ? cosf(ang) : sinf(ang);
}

// Per-lane select from (wave-uniform) SGPR-resident values: small cndmask trees.
__device__ __forceinline__ float sel4(int i, float a, float b, float c, float d) {
    float t = (i & 1) ? b : a;
    float u = (i & 1) ? d : c;
    return (i & 2) ? u : t;
}
__device__ __forceinline__ float sel3(int i, float a, float b, float c) {
    float t = (i == 1) ? b : a;
    return (i == 2) ? c : t;
}

// One wave (64 lanes) per edge, 4 waves / 256-thread block.
// All res/postab reads are wave-uniform -> scalar (s_load) path; per-lane
// variation handled by cndmask selects from SGPRs. Only 2 vector loads remain,
// hoisted to the top so their latency hides under the RBF exp chain.
extern "C" __global__ __launch_bounds__(256)
void edge_feats(const int* __restrict__ eidx,
                const int* __restrict__ seq,
                const int* __restrict__ mask,
                const float* __restrict__ res,
                const float* __restrict__ postab,
                float* __restrict__ out) {
    int lane = threadIdx.x & 63;
    int wave = threadIdx.x >> 6;
    int e = __builtin_amdgcn_readfirstlane((int)(blockIdx.x * 4 + wave));

    int dst = __builtin_amdgcn_readfirstlane(eidx[e]);
    int src = __builtin_amdgcn_readfirstlane(eidx[N_EDGE + e]);
    int msrc = mask[src];
    int mdst = mask[dst];
    float noised_src = msrc ? 1.0f : 0.0f;
    float noised_dst = mdst ? 1.0f : 0.0f;
    float keep_src = 1.0f - noised_src;
    float keep_dst = 1.0f - noised_dst;
    int ssrc = seq[src];
    int sdst = seq[dst];

    const float* rs = res + (size_t)src * 36;
    const float* rd = res + (size_t)dst * 36;
    float* op = out + (size_t)e * NFEAT;

    // ---- uniform (scalar) loads of both residue rows ----
    float rs0 = rs[0],  rs1 = rs[1],  rs2 = rs[2],  rs3 = rs[3];
    float rs4 = rs[4],  rs5 = rs[5],  rs6 = rs[6],  rs7 = rs[7];
    float rs8 = rs[8],  rs9 = rs[9],  rs10 = rs[10], rs11 = rs[11];
    float R0 = rs[24], R1 = rs[25], R2 = rs[26];
    float R3 = rs[27], R4 = rs[28], R5 = rs[29];
    float R6 = rs[30], R7 = rs[31], R8 = rs[32];
    float t0 = rs[33], t1 = rs[34], t2 = rs[35];
    float rd0 = rd[0],  rd1 = rd[1],  rd2 = rd[2],  rd3 = rd[3];
    float rd4 = rd[4],  rd5 = rd[5],  rd6 = rd[6],  rd7 = rd[7];
    float rd8 = rd[8],  rd9 = rd[9],  rd10 = rd[10], rd11 = rd[11];

    // ---- hoisted vector loads (clamped addresses, issued for all lanes) ----
    int cp = lane - 56;                       // postab chunk, valid 0..3
    int cpa = ((unsigned)cp < 4u) ? cp : 0;
    const float4 pt = *reinterpret_cast<const float4*>(
        postab + ((size_t)(dst - src + 19999) * 16 + cpa * 4));
    int cl = lane - 60;                       // src-local chunk, valid 0..2
    int cla = ((unsigned)cl < 3u) ? cl : 0;
    float4 sl = *reinterpret_cast<const float4*>(rs + 12 + 4 * cla);

    // ---------------- Phase 1: RBF block, f = 44 .. 299 ----------------
    {
        int ai = lane >> 4;          // src atom 0..3
        int aj = (lane >> 2) & 3;    // dst atom 0..3
        float sx = sel4(ai, rs0, rs3, rs6, rs9);
        float sy = sel4(ai, rs1, rs4, rs7, rs10);
        float sz = sel4(ai, rs2, rs5, rs8, rs11);
        float px = sel4(aj, rd0, rd3, rd6, rd9);
        float py = sel4(aj, rd1, rd4, rd7, rd10);
        float pz = sel4(aj, rd2, rd5, rd8, rd11);
        float dx = sx - px + 1e-8f;
        float dy = sy - py + 1e-8f;
        float dz = sz - pz + 1e-8f;
        float D = sqrtf(dx * dx + dy * dy + dz * dz);

        int rbase = (lane & 3) * 4;
        float4 v;
        float x, mu;
        mu = 2.0f + (20.0f / 15.0f) * (float)(rbase + 0);
        x = (D - mu) * 0.8f;  v.x = __expf(-x * x);
        mu = 2.0f + (20.0f / 15.0f) * (float)(rbase + 1);
        x = (D - mu) * 0.8f;  v.y = __expf(-x * x);
        mu = 2.0f + (20.0f / 15.0f) * (float)(rbase + 2);
        x = (D - mu) * 0.8f;  v.z = __expf(-x * x);
        mu = 2.0f + (20.0f / 15.0f) * (float)(rbase + 3);
        x = (D - mu) * 0.8f;  v.w = __expf(-x * x);

        *reinterpret_cast<float4*>(op + 44 + 4 * lane) = v;  // 16B-aligned
    }

    // ---------------- Phase 2: remaining 84 features ----------------
    if (lane < 44) {
        // f = lane : [noised_dst, noised_src, src one-hot(21), dst one-hot(21)]
        float v = (lane < 23) ? ((ssrc == lane - 2) ? keep_src : 0.0f)
                              : ((sdst == lane - 23) ? keep_dst : 0.0f);
        if (lane == 0) v = noised_dst;
        if (lane == 1) v = noised_src;
        op[lane] = v;
    } else if (lane < 56) {
        // dst_in_src[qq], qq = lane-44 : k = qq/3 (atom), i = qq%3 (col)
        int qq = lane - 44;
        int k = qq / 3;
        int i2 = qq - k * 3;
        float x0 = sel4(k, rd0, rd3, rd6, rd9)  - t0;
        float x1 = sel4(k, rd1, rd4, rd7, rd10) - t1;
        float x2 = sel4(k, rd2, rd5, rd8, rd11) - t2;
        float c0 = sel3(i2, R0, R1, R2);
        float c1 = sel3(i2, R3, R4, R5);
        float c2 = sel3(i2, R6, R7, R8);
        float v = (c0 * x0 + c1 * x1 + c2 * x2) * keep_dst;
        op[328 + qq] = v;
    } else if (lane < 60) {
        // positional encoding, f = 300..315 (table row chunk loaded above)
        *reinterpret_cast<float4*>(op + 300 + 4 * cp) = pt;
    } else if (lane < 63) {
        // src_bb_local * keep_src, f = 316..327 (chunk loaded above)
        float4 v = sl;
        v.x *= keep_src; v.y *= keep_src; v.z *= keep_src; v.w *= keep_src;
        *reinterpret_cast<float4*>(op + 316 + 4 * cl) = v;
    }
}

extern "C" void kernel_launch(void* const* d_in, const int* in_sizes, int n_in,
                              void* d_out, int out_size, void* d_ws, size_t ws_size,
                              hipStream_t stream) {
    const float* atom14  = (const float*)d_in[0];
    const float* rigids7 = (const float*)d_in[1];
    const int* seq  = (const int*)d_in[2];
    const int* mask = (const int*)d_in[3];
    const int* eidx = (const int*)d_in[4];
    float* res = (float*)d_ws;           // 20000*36 floats = 2.88 MB
    float* tab = res + 720000;           // 40000*16 floats = 2.56 MB (ws total 5.44 MB)

    hipLaunchKernelGGL(residue_prep, dim3((N_RES + 255) / 256), dim3(256), 0, stream,
                       atom14, rigids7, res);
    hipLaunchKernelGGL(pos_table, dim3(2500), dim3(256), 0, stream, tab);
    hipLaunchKernelGGL(edge_feats, dim3(N_EDGE / 4), dim3(256), 0, stream,
                       eidx, seq, mask, res, tab, (float*)d_out);
}

// Round 3
// 931.594 us; speedup vs baseline: 1.1260x; 1.1260x over previous
//
#include <hip/hip_runtime.h>

#define N_RES   20000
#define N_EDGE  640000
#define NFEAT   340
#define EPB     16      // edges per 256-thread block

// freq[m] = exp(2m * (-ln(10000)/16)) = 10^(-m/2)
__device__ __constant__ float c_freq[8] = {
    1.0f, 0.31622776601683794f, 0.1f, 0.031622776601683794f,
    0.01f, 0.0031622776601683794f, 0.001f, 0.00031622776601683794f};

// Per-residue precompute: bb[12] (N,CA,C,virtual CB), local[12] = R^T(bb-t),
// R[9], t[3]  -> 36 floats per residue in workspace.
extern "C" __global__ __launch_bounds__(256)
void residue_prep(const float* __restrict__ atom14,
                  const float* __restrict__ rigids7,
                  float* __restrict__ res) {
    int r = blockIdx.x * 256 + threadIdx.x;
    if (r >= N_RES) return;

    const float* a = atom14 + (size_t)r * 42;  // 14 atoms * 3
    float nx  = a[0], ny  = a[1], nz  = a[2];
    float cax = a[3], cay = a[4], caz = a[5];
    float cx  = a[6], cy  = a[7], cz  = a[8];

    // virtual CB
    float bx = cax - nx, by = cay - ny, bz = caz - nz;     // b  = ca - n
    float ex = cx - cax, ey = cy - cay, ez = cz - caz;     // cc = c - ca
    float ax = by * ez - bz * ey;                          // a = cross(b, cc)
    float ay = bz * ex - bx * ez;
    float az = bx * ey - by * ex;
    float cbx = -0.58273431f * ax + 0.56802827f * bx - 0.54067466f * ex + cax;
    float cby = -0.58273431f * ay + 0.56802827f * by - 0.54067466f * ey + cay;
    float cbz = -0.58273431f * az + 0.56802827f * bz - 0.54067466f * ez + caz;

    const float* q7 = rigids7 + (size_t)r * 7;
    float qw = q7[0], qx = q7[1], qy = q7[2], qz = q7[3];
    float inv = 1.0f / sqrtf(qw * qw + qx * qx + qy * qy + qz * qz);
    qw *= inv; qx *= inv; qy *= inv; qz *= inv;
    float tx = q7[4], ty = q7[5], tz = q7[6];

    // R[j*3+i] : row j, col i (matches _quat_to_rot stacking)
    float R[9];
    R[0] = 1.0f - 2.0f * (qy * qy + qz * qz);
    R[1] = 2.0f * (qx * qy - qw * qz);
    R[2] = 2.0f * (qx * qz + qw * qy);
    R[3] = 2.0f * (qx * qy + qw * qz);
    R[4] = 1.0f - 2.0f * (qx * qx + qz * qz);
    R[5] = 2.0f * (qy * qz - qw * qx);
    R[6] = 2.0f * (qx * qz - qw * qy);
    R[7] = 2.0f * (qy * qz + qw * qx);
    R[8] = 1.0f - 2.0f * (qx * qx + qy * qy);

    float bb[12] = {nx, ny, nz, cax, cay, caz, cx, cy, cz, cbx, cby, cbz};

    float* o = res + (size_t)r * 36;
    #pragma unroll
    for (int k = 0; k < 12; ++k) o[k] = bb[k];
    // local[k][i] = sum_j R[j][i] * (bb[k][j] - t[j])   (R^T * x)
    #pragma unroll
    for (int k = 0; k < 4; ++k) {
        float x0 = bb[k * 3 + 0] - tx;
        float x1 = bb[k * 3 + 1] - ty;
        float x2 = bb[k * 3 + 2] - tz;
        #pragma unroll
        for (int i = 0; i < 3; ++i)
            o[12 + k * 3 + i] = R[i] * x0 + R[3 + i] * x1 + R[6 + i] * x2;
    }
    #pragma unroll
    for (int j = 0; j < 9; ++j) o[24 + j] = R[j];
    o[33] = tx; o[34] = ty; o[35] = tz;
}

// Positional-encoding table: dpos = dst-src is an INTEGER in [-19999,19999].
// tab[row][0..7] = cos(d*freq[m]), tab[row][8..15] = sin(d*freq[m]), d = row-19999.
extern "C" __global__ __launch_bounds__(256)
void pos_table(float* __restrict__ tab) {
    int idx = blockIdx.x * 256 + threadIdx.x;   // 0 .. 640000-1 (40000 rows * 16)
    int row = idx >> 4;
    int m = idx & 15;
    float d = (float)(row - 19999);
    float ang = d * c_freq[m & 7];
    tab[idx] = (m < 8) ? cosf(ang) : sinf(ang);
}

// Block = 256 threads = 16 edges. Gather phase: each thread fetches ONE float4
// of operand data (rs[36] / rd bb[12] / postab[16] = 16 chunks per edge) into
// LDS -> 256 independent loads in flight per block. Wave 0 also fetches the
// seq/mask scalars. One barrier, then each wave computes 4 edges entirely from
// LDS (broadcast reads), so the compute path has zero global-load latency.
extern "C" __global__ __launch_bounds__(256)
void edge_feats(const int* __restrict__ eidx,
                const int* __restrict__ seq,
                const int* __restrict__ mask,
                const float* __restrict__ res,
                const float* __restrict__ postab,
                float* __restrict__ out) {
    // per-edge LDS row (64 floats): [0..35]=rs row, [36..47]=rd bb, [48..63]=postab row
    __shared__ __align__(16) float sm[EPB * 64];
    __shared__ int s_sd[EPB], s_ss[EPB], s_md[EPB], s_ms[EPB];

    int tid = threadIdx.x;
    int ebase = blockIdx.x * EPB;
    int el = tid >> 4;        // edge slot 0..15
    int c  = tid & 15;        // chunk 0..15

    int rdst = eidx[ebase + el];            // 16-wide broadcast-coalesced
    int rsrc = eidx[N_EDGE + ebase + el];

    const float* gp;
    int loff;
    if (c < 9)       { gp = res + (size_t)rsrc * 36 + c * 4;                         loff = c * 4; }
    else if (c < 12) { gp = res + (size_t)rdst * 36 + (c - 9) * 4;                   loff = 36 + (c - 9) * 4; }
    else             { gp = postab + (size_t)(rdst - rsrc + 19999) * 16 + (c - 12) * 4; loff = 48 + (c - 12) * 4; }
    float4 gv = *reinterpret_cast<const float4*>(gp);
    *reinterpret_cast<float4*>(&sm[el * 64 + loff]) = gv;

    if (tid < 64) {
        int q = tid >> 4, e2 = tid & 15;
        int idx = (q & 1) ? eidx[N_EDGE + ebase + e2] : eidx[ebase + e2];
        int v = (q < 2) ? seq[idx] : mask[idx];
        if (q == 0) s_sd[e2] = v;
        else if (q == 1) s_ss[e2] = v;
        else if (q == 2) s_md[e2] = v;
        else s_ms[e2] = v;
    }
    __syncthreads();

    int lane = tid & 63;
    int wave = tid >> 6;

    #pragma unroll
    for (int i = 0; i < 4; ++i) {
        int eloc = wave * 4 + i;
        int e = ebase + eloc;
        const float* L = sm + eloc * 64;
        int ssrc = s_ss[eloc];
        int sdst = s_sd[eloc];
        float noised_src = s_ms[eloc] ? 1.0f : 0.0f;
        float noised_dst = s_md[eloc] ? 1.0f : 0.0f;
        float keep_src = 1.0f - noised_src;
        float keep_dst = 1.0f - noised_dst;
        float* op = out + (size_t)e * NFEAT;

        // ---------------- Phase 1: RBF block, f = 44 .. 299 ----------------
        {
            int ai = lane >> 4;          // src atom 0..3
            int aj = (lane >> 2) & 3;    // dst atom 0..3
            float sx = L[ai * 3 + 0], sy = L[ai * 3 + 1], sz = L[ai * 3 + 2];
            float px = L[36 + aj * 3 + 0], py = L[36 + aj * 3 + 1], pz = L[36 + aj * 3 + 2];
            float dx = sx - px + 1e-8f;
            float dy = sy - py + 1e-8f;
            float dz = sz - pz + 1e-8f;
            float D = sqrtf(dx * dx + dy * dy + dz * dz);

            int rbase = (lane & 3) * 4;
            float4 v;
            float x, mu;
            mu = 2.0f + (20.0f / 15.0f) * (float)(rbase + 0);
            x = (D - mu) * 0.8f;  v.x = __expf(-x * x);
            mu = 2.0f + (20.0f / 15.0f) * (float)(rbase + 1);
            x = (D - mu) * 0.8f;  v.y = __expf(-x * x);
            mu = 2.0f + (20.0f / 15.0f) * (float)(rbase + 2);
            x = (D - mu) * 0.8f;  v.z = __expf(-x * x);
            mu = 2.0f + (20.0f / 15.0f) * (float)(rbase + 3);
            x = (D - mu) * 0.8f;  v.w = __expf(-x * x);

            *reinterpret_cast<float4*>(op + 44 + 4 * lane) = v;  // 16B-aligned
        }

        // ---------------- Phase 2: remaining 84 features ----------------
        if (lane < 44) {
            // f = lane : [noised_dst, noised_src, src one-hot(21), dst one-hot(21)]
            float v = (lane < 23) ? ((ssrc == lane - 2) ? keep_src : 0.0f)
                                  : ((sdst == lane - 23) ? keep_dst : 0.0f);
            if (lane == 0) v = noised_dst;
            if (lane == 1) v = noised_src;
            op[lane] = v;
        } else if (lane < 56) {
            // dst_in_src[qq], qq = lane-44 : k = qq/3 (atom), i = qq%3 (col)
            int qq = lane - 44;
            int k = qq / 3;
            int i2 = qq - k * 3;
            float x0 = L[36 + k * 3 + 0] - L[33];
            float x1 = L[36 + k * 3 + 1] - L[34];
            float x2 = L[36 + k * 3 + 2] - L[35];
            float v = (L[24 + i2] * x0 + L[27 + i2] * x1 + L[30 + i2] * x2) * keep_dst;
            op[328 + qq] = v;
        } else if (lane < 60) {
            // positional encoding, f = 300..315 (table row staged in LDS)
            int cc = lane - 56;
            float4 pt = *reinterpret_cast<const float4*>(&L[48 + 4 * cc]);
            *reinterpret_cast<float4*>(op + 300 + 4 * cc) = pt;
        } else if (lane < 63) {
            // src_bb_local * keep_src, f = 316..327
            int cc = lane - 60;
            float4 sl = *reinterpret_cast<const float4*>(&L[12 + 4 * cc]);
            sl.x *= keep_src; sl.y *= keep_src; sl.z *= keep_src; sl.w *= keep_src;
            *reinterpret_cast<float4*>(op + 316 + 4 * cc) = sl;
        }
    }
}

extern "C" void kernel_launch(void* const* d_in, const int* in_sizes, int n_in,
                              void* d_out, int out_size, void* d_ws, size_t ws_size,
                              hipStream_t stream) {
    const float* atom14  = (const float*)d_in[0];
    const float* rigids7 = (const float*)d_in[1];
    const int* seq  = (const int*)d_in[2];
    const int* mask = (const int*)d_in[3];
    const int* eidx = (const int*)d_in[4];
    float* res = (float*)d_ws;           // 20000*36 floats = 2.88 MB
    float* tab = res + 720000;           // 40000*16 floats = 2.56 MB (ws total 5.44 MB)

    hipLaunchKernelGGL(residue_prep, dim3((N_RES + 255) / 256), dim3(256), 0, stream,
                       atom14, rigids7, res);
    hipLaunchKernelGGL(pos_table, dim3(2500), dim3(256), 0, stream, tab);
    hipLaunchKernelGGL(edge_feats, dim3(N_EDGE / EPB), dim3(256), 0, stream,
                       eidx, seq, mask, res, tab, (float*)d_out);
}